// Round 1
// baseline (385.116 us; speedup 1.0000x reference)
//
#include <hip/hip_runtime.h>

#define SEQ   1024
#define BATCH 1024
#define TAG   32
#define START 30      // TAG-2
#define ENDT  31      // TAG-1
#define PFD   8       // prefetch ring depth (steps)

__device__ __forceinline__ float rdlane(float v, int j) {
    return __uint_as_float(__builtin_amdgcn_readlane(__float_as_uint(v), j));
}

// Core CRF step. Phase 1: 32 back-to-back v_readlane (SGPR gather).
// sched_barrier(0) pins the boundary so the readlane->VALU SGPR hazard
// (~5 wait states) is paid ONCE, not 32x (the 527 cy/step floor).
// Produces (does NOT commit):
//   vn_i = (sum_j v_j * E[i][j]) * exp(fval) / c,   lg = log(c)
// with c = max(v_0, 1e-20) -- the guard covers the one-hot start state
// (v_0 == 0 before the first active step). Committing {v = vn, mA += lg}
// advances one step of the invariant alpha_i = mA + log(v_i).
__device__ __forceinline__ void crf_core(float v, float fval,
                                         const float* __restrict__ e,
                                         float& vn, float& lg) {
    float r[32];
    #pragma unroll
    for (int j = 0; j < 32; ++j) r[j] = rdlane(v, j);
    __builtin_amdgcn_sched_barrier(0);

    float s0 = r[0] * e[0];
    float s1 = r[1] * e[1];
    float s2 = r[2] * e[2];
    float s3 = r[3] * e[3];
    float s4 = r[4] * e[4];
    float s5 = r[5] * e[5];
    float s6 = r[6] * e[6];
    float s7 = r[7] * e[7];
    #pragma unroll
    for (int j = 1; j < 4; ++j) {
        s0 = fmaf(r[8 * j + 0], e[8 * j + 0], s0);
        s1 = fmaf(r[8 * j + 1], e[8 * j + 1], s1);
        s2 = fmaf(r[8 * j + 2], e[8 * j + 2], s2);
        s3 = fmaf(r[8 * j + 3], e[8 * j + 3], s3);
        s4 = fmaf(r[8 * j + 4], e[8 * j + 4], s4);
        s5 = fmaf(r[8 * j + 5], e[8 * j + 5], s5);
        s6 = fmaf(r[8 * j + 6], e[8 * j + 6], s6);
        s7 = fmaf(r[8 * j + 7], e[8 * j + 7], s7);
    }
    float dot = ((s0 + s1) + (s2 + s3)) + ((s4 + s5) + (s6 + s7));

    float c  = fmaxf(r[0], 1e-20f);               // off-chain (ready after readlane 0)
    float ef = __expf(fval);                      // off-chain
    float rr = __builtin_amdgcn_rcpf(c);          // off-chain
    lg = __logf(c);                               // off-chain (mA only)
    float sc = ef * rr;                           // off-chain combine
    vn = dot * sc;                                // single on-chain mul
}

// One wave = one batch; lanes 0..31 == 32..63 (tag i = lane&31).
// Invariant: alpha_i = mA + ln(v_i); v renormalized by max(v[0],1e-20) on commit.
// Mask is applied PER STEP with the reference's exact semantics
// (alpha' = m*new + (1-m)*old): m==1 -> commit, m==0 -> skip (scalar branch,
// ~free, so trailing-masked waves fast-forward), fractional m -> log-domain
// blend. No monotone-prefix / binary assumption on mask.
__global__ __attribute__((amdgpu_waves_per_eu(1, 1)))
__launch_bounds__(64, 1) void crf_fwd_kernel(
    const float* __restrict__ feats,   // (SEQ, BATCH, TAG)
    const float* __restrict__ mask,    // (SEQ, BATCH)
    const float* __restrict__ trans,   // (TAG, TAG)
    float* __restrict__ out)           // (BATCH,)
{
    const int lane = threadIdx.x;
    const int i    = lane & 31;
    const int b    = blockIdx.x;

    // ---- E[i][j] = exp(trans[i][j]); NEG entries underflow to exactly 0 ----
    float e[32];
    {
        const float4* tr4 = reinterpret_cast<const float4*>(trans + i * TAG);
        #pragma unroll
        for (int c = 0; c < 8; ++c) {
            float4 t = tr4[c];
            e[4 * c + 0] = __expf(t.x);
            e[4 * c + 1] = __expf(t.y);
            e[4 * c + 2] = __expf(t.z);
            e[4 * c + 3] = __expf(t.w);
        }
    }

    const float* fp = feats + (unsigned)(b * TAG + i);
    const float* mk = mask + (unsigned)b;

    // ---- start state: alpha0 = NEG except START=0  ->  v one-hot, mA = 0 ----
    float  v  = (i == START) ? 1.0f : 0.0f;
    double mA = 0.0;

    // ---- prefetch rings (feat + mask) for t = 0..PFD-1 ----
    float fb[PFD], mb[PFD];
    #pragma unroll
    for (int p = 0; p < PFD; ++p) {
        fb[p] = fp[(unsigned)p << 15];
        mb[p] = mk[(unsigned)p << 10];
    }

    for (int t = 0; t < SEQ; t += PFD) {
        #pragma unroll
        for (int p = 0; p < PFD; ++p) {
            // mask is per-batch => wave-uniform; branch on SGPR bits.
            unsigned mu = __builtin_amdgcn_readfirstlane(__float_as_uint(mb[p]));
            if (mu != 0u) {
                float vn, lg;
                crf_core(v, fb[p], e, vn, lg);
                if (mu == 0x3f800000u) {          // m == 1.0f: plain commit
                    v = vn;
                    mA += (double)lg;
                } else {                          // fractional m: exact blend
                    float m   = __uint_as_float(mu);
                    float lv  = __logf(fmaxf(v,  1e-37f));
                    float lvn = __logf(fmaxf(vn, 1e-37f));
                    v = v * __expf(m * (lvn - lv));   // v=0 lanes stay exactly 0
                    mA += (double)(m * lg);
                }
            }
            int tn = t + PFD + p; tn = (tn < SEQ) ? tn : (SEQ - 1);
            fb[p] = fp[(unsigned)tn << 15];
            mb[p] = mk[(unsigned)tn << 10];
        }
    }

    // ---- epilogue: out[b] = mA + ln( sum_i v_i * exp(trans[END][i]) ) ----
    float z = v * __expf(trans[ENDT * TAG + i]);
    float mx = z;
    #pragma unroll
    for (int k = 16; k >= 1; k >>= 1)
        mx = fmaxf(mx, __shfl_xor(mx, k, 32));
    float ss = z * __builtin_amdgcn_rcpf(mx);   // mx > 0 (some v_i > 0 always)
    #pragma unroll
    for (int k = 16; k >= 1; k >>= 1)
        ss += __shfl_xor(ss, k, 32);
    if (lane == 0)
        out[b] = (float)(mA + (double)__logf(mx) + (double)__logf(ss));
}

extern "C" void kernel_launch(void* const* d_in, const int* in_sizes, int n_in,
                              void* d_out, int out_size, void* d_ws, size_t ws_size,
                              hipStream_t stream) {
    const float* feats = (const float*)d_in[0];
    const float* mask  = (const float*)d_in[1];
    const float* trans = (const float*)d_in[2];
    float* out = (float*)d_out;
    crf_fwd_kernel<<<dim3(BATCH), dim3(64), 0, stream>>>(feats, mask, trans, out);
}

// Round 6
// 319.493 us; speedup vs baseline: 1.2054x; 1.2054x over previous
//
#include <hip/hip_runtime.h>

#define SEQ   1024
#define BATCH 1024
#define TAG   32
#define START 30      // TAG-2
#define ENDT  31      // TAG-1
#define PFD   8       // prefetch ring depth (steps)
#define HALF  512     // steps per wave (fwd wave: 0..511, bwd wave: 1023..512)

__device__ __forceinline__ float rdlane(float v, int j) {
    return __uint_as_float(__builtin_amdgcn_readlane(__float_as_uint(v), j));
}

// ---- verified scalar core (r1): gather 32 lanes, 8-way dot, renorm ----
// vn = (sum_j coef[j] * v_j) * post * rcp(c),  lg = log(c),  c = max(v_0,1e-20).
// log(c) pairs with rcp(c): any positive c is algebraically exact (drift ~1e-7).
__device__ __forceinline__ void gather_dot(float v, const float* __restrict__ coef,
                                           float post, float& vn, float& lg) {
    float r[32];
    #pragma unroll
    for (int j = 0; j < 32; ++j) r[j] = rdlane(v, j);
    __builtin_amdgcn_sched_barrier(0);

    float s0 = r[0] * coef[0];
    float s1 = r[1] * coef[1];
    float s2 = r[2] * coef[2];
    float s3 = r[3] * coef[3];
    float s4 = r[4] * coef[4];
    float s5 = r[5] * coef[5];
    float s6 = r[6] * coef[6];
    float s7 = r[7] * coef[7];
    #pragma unroll
    for (int j = 1; j < 4; ++j) {
        s0 = fmaf(r[8 * j + 0], coef[8 * j + 0], s0);
        s1 = fmaf(r[8 * j + 1], coef[8 * j + 1], s1);
        s2 = fmaf(r[8 * j + 2], coef[8 * j + 2], s2);
        s3 = fmaf(r[8 * j + 3], coef[8 * j + 3], s3);
        s4 = fmaf(r[8 * j + 4], coef[8 * j + 4], s4);
        s5 = fmaf(r[8 * j + 5], coef[8 * j + 5], s5);
        s6 = fmaf(r[8 * j + 6], coef[8 * j + 6], s6);
        s7 = fmaf(r[8 * j + 7], coef[8 * j + 7], s7);
    }
    float dot = ((s0 + s1) + (s2 + s3)) + ((s4 + s5) + (s6 + s7));

    float c  = fmaxf(r[0], 1e-20f);               // off-chain after readlane 0
    float rr = __builtin_amdgcn_rcpf(c);
    lg = __logf(c);                               // feeds mA/mB only
    float sc = post * rr;                         // off-chain combine
    vn = dot * sc;                                // single on-chain mul
}

// ---------------- slow fallback (r1 verbatim: per-step exact blend) --------
__device__ __forceinline__ void crf_core(float v, float fval,
                                         const float* __restrict__ e,
                                         float& vn, float& lg) {
    gather_dot(v, e, __expf(fval), vn, lg);
}

__device__ void slow_path(const float* __restrict__ feats,
                          const float* __restrict__ mask,
                          const float* __restrict__ trans,
                          float* __restrict__ out, int b, int lane) {
    const int i = lane & 31;
    float e[32];
    {
        const float4* tr4 = reinterpret_cast<const float4*>(trans + i * TAG);
        #pragma unroll
        for (int c = 0; c < 8; ++c) {
            float4 t = tr4[c];
            e[4 * c + 0] = __expf(t.x);
            e[4 * c + 1] = __expf(t.y);
            e[4 * c + 2] = __expf(t.z);
            e[4 * c + 3] = __expf(t.w);
        }
    }
    const float* fp = feats + (unsigned)(b * TAG + i);
    const float* mk = mask + (unsigned)b;

    float  v  = (i == START) ? 1.0f : 0.0f;
    double mA = 0.0;

    float fb[PFD], mb[PFD];
    #pragma unroll
    for (int p = 0; p < PFD; ++p) {
        fb[p] = fp[(unsigned)p << 15];
        mb[p] = mk[(unsigned)p << 10];
    }
    for (int t = 0; t < SEQ; t += PFD) {
        #pragma unroll
        for (int p = 0; p < PFD; ++p) {
            unsigned mu = __builtin_amdgcn_readfirstlane(__float_as_uint(mb[p]));
            float fv = fb[p];
            int tn = t + PFD + p; tn = (tn < SEQ) ? tn : (SEQ - 1);
            fb[p] = fp[(unsigned)tn << 15];
            mb[p] = mk[(unsigned)tn << 10];
            if (mu != 0u) {
                float vn, lg;
                crf_core(v, fv, e, vn, lg);
                if (mu == 0x3f800000u) {
                    v = vn;
                    mA += (double)lg;
                } else {
                    float m   = __uint_as_float(mu);
                    float lv  = __logf(fmaxf(v,  1e-37f));
                    float lvn = __logf(fmaxf(vn, 1e-37f));
                    v = v * __expf(m * (lvn - lv));
                    mA += (double)(m * lg);
                }
            }
        }
    }
    float z = v * __expf(trans[ENDT * TAG + i]);
    float mx = z;
    #pragma unroll
    for (int k = 16; k >= 1; k >>= 1)
        mx = fmaxf(mx, __shfl_xor(mx, k, 32));
    float ss = z * __builtin_amdgcn_rcpf(mx);
    #pragma unroll
    for (int k = 16; k >= 1; k >>= 1)
        ss += __shfl_xor(ss, k, 32);
    if (lane == 0)
        out[b] = (float)(mA + (double)__logf(mx) + (double)__logf(ss));
}

// ---------------- fast path: forward-backward split ------------------------
// logZ = log( e~^T * M1~ * M0~ * e_START ),  e~_i = exp(trans[END][i]).
// Wave 0 (forward):  x <- D_t A x,  t = 0..511       (x0 = e_START)
// Wave 1 (backward): y <- A^T D_t y, t = 1023..512   (y0 = e~)
//   per-lane: u = y * exp(f_t),  y'_j = sum_i E[i][j] * u_i  (eT table)
// Masked steps are identity => uniform-branch skip in both directions.
// Combine: out = mA + mB + log( sum_i x_i y_i ).
__global__ __launch_bounds__(128, 2) void crf_fwd_kernel(
    const float* __restrict__ feats,   // (SEQ, BATCH, TAG)
    const float* __restrict__ mask,    // (SEQ, BATCH)
    const float* __restrict__ trans,   // (TAG, TAG)
    float* __restrict__ out)           // (BATCH,)
{
    const int tid  = threadIdx.x;
    const int lane = tid & 63;
    const int w    = tid >> 6;          // 0 = forward wave, 1 = backward wave
    const int i    = lane & 31;
    const int b    = blockIdx.x;

    __shared__ float  sX[32], sY[32];
    __shared__ double sM[2];
    __shared__ int    sFrac;

    if (tid == 0) sFrac = 0;
    __syncthreads();

    // prepass over own half: binary mask?
    {
        const int tb = w * HALF;
        bool bad = false;
        #pragma unroll
        for (int k = 0; k < 8; ++k) {
            float m = mask[(unsigned)((tb + k * 64 + lane) * BATCH + b)];
            bad |= (m != 0.0f) & (m != 1.0f);
        }
        if (__ballot(bad)) sFrac = 1;
    }
    __syncthreads();

    if (sFrac) {                        // fractional masks: exact blend path
        if (w == 0) slow_path(feats, mask, trans, out, b, lane);
        return;
    }

    const float* fp = feats + (unsigned)(b * TAG + i);
    const float* mk = mask + (unsigned)b;

    if (w == 0) {
        // ---- forward: coef row-major, e[j] = exp(trans[i][j]) ----
        float e[32];
        const float4* tr4 = reinterpret_cast<const float4*>(trans + i * TAG);
        #pragma unroll
        for (int c = 0; c < 8; ++c) {
            float4 t = tr4[c];
            e[4 * c + 0] = __expf(t.x);
            e[4 * c + 1] = __expf(t.y);
            e[4 * c + 2] = __expf(t.z);
            e[4 * c + 3] = __expf(t.w);
        }
        float  v  = (i == START) ? 1.0f : 0.0f;   // x0 = e_START (guard handles v0=0)
        double mA = 0.0;

        float fb[PFD], mb[PFD];
        #pragma unroll
        for (int p = 0; p < PFD; ++p) {
            fb[p] = fp[(unsigned)p << 15];
            mb[p] = mk[(unsigned)p << 10];
        }
        for (int t = 0; t < HALF; t += PFD) {
            #pragma unroll
            for (int p = 0; p < PFD; ++p) {
                unsigned mu = __builtin_amdgcn_readfirstlane(__float_as_uint(mb[p]));
                float fv = fb[p];
                int tn = t + PFD + p;            // reads ahead into 512..519: harmless
                fb[p] = fp[(unsigned)tn << 15];
                mb[p] = mk[(unsigned)tn << 10];
                if (mu != 0u) {
                    float vn, lg;
                    gather_dot(v, e, __expf(fv), vn, lg);
                    v = vn; mA += (double)lg;
                }
            }
        }
        if (lane < 32) sX[i] = v;
        if (lane == 0) sM[0] = mA;
    } else {
        // ---- backward: coef column-major, eT[c] = exp(trans[c][i]) ----
        float eT[32];
        #pragma unroll
        for (int c = 0; c < 32; ++c)
            eT[c] = __expf(trans[c * TAG + i]);   // coalesced across lanes
        float  y  = __expf(trans[ENDT * TAG + i]); // y0 = e~ (END entry -> 0)
        double mB = 0.0;

        float fb[PFD], mb[PFD];
        #pragma unroll
        for (int p = 0; p < PFD; ++p) {
            fb[p] = fp[(unsigned)(SEQ - 1 - p) << 15];
            mb[p] = mk[(unsigned)(SEQ - 1 - p) << 10];
        }
        for (int s = 0; s < HALF; s += PFD) {
            #pragma unroll
            for (int p = 0; p < PFD; ++p) {
                unsigned mu = __builtin_amdgcn_readfirstlane(__float_as_uint(mb[p]));
                float fv = fb[p];
                int tn = SEQ - 1 - (s + PFD + p); // reads down to 504: harmless
                fb[p] = fp[(unsigned)tn << 15];
                mb[p] = mk[(unsigned)tn << 10];
                if (mu != 0u) {
                    float u = y * __expf(fv);     // D_t scale (exp fed off-chain)
                    float yn, lg;
                    gather_dot(u, eT, 1.0f, yn, lg);
                    y = yn; mB += (double)lg;
                }
            }
        }
        if (lane < 32) sY[i] = y;
        if (lane == 0) sM[1] = mB;
    }
    __syncthreads();

    // ---- combine (wave 0): out = mA + mB + log(sum_i x_i y_i) ----
    if (w == 0) {
        float z = sX[i] * sY[i];                  // all >= 0
        float mx = z;
        #pragma unroll
        for (int k = 16; k >= 1; k >>= 1)
            mx = fmaxf(mx, __shfl_xor(mx, k, 32));
        mx = fmaxf(mx, 1e-30f);
        float ss = z * __builtin_amdgcn_rcpf(mx);
        #pragma unroll
        for (int k = 16; k >= 1; k >>= 1)
            ss += __shfl_xor(ss, k, 32);
        if (lane == 0)
            out[b] = (float)(sM[0] + sM[1]
                             + (double)__logf(mx) + (double)__logf(ss));
    }
}

extern "C" void kernel_launch(void* const* d_in, const int* in_sizes, int n_in,
                              void* d_out, int out_size, void* d_ws, size_t ws_size,
                              hipStream_t stream) {
    const float* feats = (const float*)d_in[0];
    const float* mask  = (const float*)d_in[1];
    const float* trans = (const float*)d_in[2];
    float* out = (float*)d_out;
    crf_fwd_kernel<<<dim3(BATCH), dim3(128), 0, stream>>>(feats, mask, trans, out);
}